// Round 11
// baseline (94.225 us; speedup 1.0000x reference)
//
#include <hip/hip_runtime.h>

// ChannelAttention on MI355X (gfx950) — R10: fused split-bf16 MFMA, 8 waves
// B=128, HW=256, C=1024, S=32, EMB=256, IDF=256(==HW)
//
// out[b,p,c] = sum_s we[b,s,p] * softmax_s( sum_p' wc[b,p',c] * we[b,s,p'] )
// attn[b,c,s] = softmax probabilities
// d_out: out (128*256*1024 f32) then attn (128*1024*32 f32)
// d_ws : KmT hi/lo bf16 [p][e] (128 KB + 128 KB)
//
// R9 counters (Mfma 6%, VALU 21%, HBM 44%, conflicts negligible): TLP+ILP
// shortage at 2 waves/SIMD with unprefetched scalar Km loads. R10:
//  - 512-thr blocks (8 waves; wave owns 32 c / 32 p), LDS 74.7KB -> 2
//    blocks/CU -> 4 waves/SIMD (launch_bounds(512,4), VGPR<=128)
//  - Km pre-split+transposed to bf16 hi/lo KmT[p][e]: proj B-frag = one
//    contiguous 16B load, no in-loop convert
//  - full-kt ping-pong prefetch in proj AND phase A; P-frag prefetch in B
// MFMA layouts (R8/R9 HW-verified):
//   A[M][K]: row=l&15, k=(l>>4)*8+i ; B[K][N]: col=l&15, same k
//   C/D: col=l&15, row=(l>>4)*4+reg

typedef float  f32x4  __attribute__((ext_vector_type(4)));
typedef short  bf16x8 __attribute__((ext_vector_type(8)));

namespace {
constexpr int kB = 128, kHW = 256, kC = 1024, kS = 32, kE = 256;
constexpr int TP = kHW + 8;  // 264 u16 row stride
constexpr int WR = kS + 8;   // 40 u16 row stride
}

__device__ inline ushort f2bf(float x) {             // f32 -> bf16 RNE
  unsigned u = __float_as_uint(x);
  u += 0x7fffu + ((u >> 16) & 1u);
  return (ushort)(u >> 16);
}
__device__ inline float bf2f(ushort h) { return __uint_as_float(((unsigned)h) << 16); }

#define MFMA16(A, Bf, Cv) __builtin_amdgcn_mfma_f32_16x16x32_bf16((A), (Bf), (Cv), 0, 0, 0)

// KmT_h/KmT_l[p][e] = split( Km[e][p] ).  grid 256 (p), 256 thr (e).
__global__ __launch_bounds__(256) void km_prep_kernel(
    const float* __restrict__ Km, ushort* __restrict__ kh,
    ushort* __restrict__ kl) {
  const int p = blockIdx.x, e = threadIdx.x;
  const float v = Km[(size_t)e * kHW + p];
  const ushort h = f2bf(v);
  kh[(size_t)p * kE + e] = h;
  kl[(size_t)p * kE + e] = (ushort)f2bf(v - bf2f(h));
}

// grid (4,128), 512 thr = 8 waves; block: one b, 256 channels.
__global__ __launch_bounds__(512, 4) void fused_attn_kernel(
    const float* __restrict__ wc, const float* __restrict__ emb,
    const ushort* __restrict__ kmh, const ushort* __restrict__ kml,
    const float* __restrict__ bias, float* __restrict__ out,
    float* __restrict__ attn_out) {
  const int b    = blockIdx.y;
  const int cb   = blockIdx.x * 256;
  const int tid  = threadIdx.x;
  const int wave = tid >> 6, lane = tid & 63;
  const int lr   = lane & 15, lg = lane >> 4;

  __shared__ ushort wHT[kS][TP];    // weT^T hi [s][p]
  __shared__ ushort wLT[kS][TP];    // weT^T lo [s][p]
  __shared__ ushort wHp[kHW][WR];   // weT  hi  [p][s]
  __shared__ ushort pHl[kHW][WR];   // P    hi  [c][s]

  const float* wcb = wc + (size_t)b * kHW * kC;
  const int c0 = cb + wave * 32;        // phase-A: wave owns 32 c
  const int p0 = wave * 32;             // proj/phase-B: wave owns 32 p

  // ================= projection: weT[s][p] = emb x K =================
  {
    const float* embb = emb + (size_t)b * kS * kE;
    f32x4 pcc[2][2];
#pragma unroll
    for (int m = 0; m < 2; ++m)
#pragma unroll
      for (int n = 0; n < 2; ++n) pcc[m][n] = (f32x4){0.f, 0.f, 0.f, 0.f};

    float4 eC[2][2]; bf16x8 khC[2], klC[2];
#pragma unroll
    for (int m = 0; m < 2; ++m) {
      const float* ep = embb + (size_t)(m * 16 + lr) * kE + lg * 8;
      eC[m][0] = *(const float4*)ep;
      eC[m][1] = *(const float4*)(ep + 4);
    }
#pragma unroll
    for (int n = 0; n < 2; ++n) {
      const int pg = p0 + n * 16 + lr;
      khC[n] = *(const bf16x8*)&kmh[(size_t)pg * kE + lg * 8];
      klC[n] = *(const bf16x8*)&kml[(size_t)pg * kE + lg * 8];
    }

#pragma unroll 1
    for (int kt = 0; kt < 8; ++kt) {
      float4 eN[2][2]; bf16x8 khN[2], klN[2];
      if (kt < 7) {
        const int ko = (kt + 1) * 32;
#pragma unroll
        for (int m = 0; m < 2; ++m) {
          const float* ep = embb + (size_t)(m * 16 + lr) * kE + ko + lg * 8;
          eN[m][0] = *(const float4*)ep;
          eN[m][1] = *(const float4*)(ep + 4);
        }
#pragma unroll
        for (int n = 0; n < 2; ++n) {
          const int pg = p0 + n * 16 + lr;
          khN[n] = *(const bf16x8*)&kmh[(size_t)pg * kE + ko + lg * 8];
          klN[n] = *(const bf16x8*)&kml[(size_t)pg * kE + ko + lg * 8];
        }
      }
      bf16x8 eah[2], eal[2];
#pragma unroll
      for (int m = 0; m < 2; ++m) {
        const float* ev = (const float*)&eC[m][0];
#pragma unroll
        for (int i = 0; i < 8; ++i) {
          const ushort h = f2bf(ev[i]);
          eah[m][i] = (short)h;
          eal[m][i] = (short)f2bf(ev[i] - bf2f(h));
        }
      }
#pragma unroll
      for (int n = 0; n < 2; ++n)
#pragma unroll
        for (int m = 0; m < 2; ++m) {
          pcc[m][n] = MFMA16(eah[m], khC[n], pcc[m][n]);
          pcc[m][n] = MFMA16(eah[m], klC[n], pcc[m][n]);
          pcc[m][n] = MFMA16(eal[m], khC[n], pcc[m][n]);
        }
      if (kt < 7) {
#pragma unroll
        for (int m = 0; m < 2; ++m) { eC[m][0] = eN[m][0]; eC[m][1] = eN[m][1]; }
#pragma unroll
        for (int n = 0; n < 2; ++n) { khC[n] = khN[n]; klC[n] = klN[n]; }
      }
    }
    // bias + split + write both LDS layouts
#pragma unroll
    for (int n = 0; n < 2; ++n) {
      const int pg = p0 + n * 16 + lr;
      const float bv = bias[pg];
#pragma unroll
      for (int m = 0; m < 2; ++m)
#pragma unroll
        for (int j = 0; j < 4; ++j) {
          const float x = pcc[m][n][j] + bv;
          const ushort h = f2bf(x);
          const int s = m * 16 + lg * 4 + j;
          wHT[s][pg] = h;
          wLT[s][pg] = (ushort)f2bf(x - bf2f(h));
          wHp[pg][s] = h;
        }
    }
  }

  // issue phase-A kt=0 wc prefetch before the barrier
  float avC[2][8], avN[2][8];
#pragma unroll
  for (int m = 0; m < 2; ++m)
#pragma unroll
    for (int i = 0; i < 8; ++i)
      avC[m][i] = wcb[(size_t)(lg * 8 + i) * kC + c0 + m * 16 + lr];

  __syncthreads();

  // ======= Phase A: D[c][s] = wc^T x weT^T; K=256, 2 m-tiles x 2 n =======
  f32x4 acc[2][2];
#pragma unroll
  for (int m = 0; m < 2; ++m)
#pragma unroll
    for (int n = 0; n < 2; ++n) acc[m][n] = (f32x4){0.f, 0.f, 0.f, 0.f};

#pragma unroll 1
  for (int kt = 0; kt < 8; ++kt) {
    bf16x8 bh[2], bl[2];
#pragma unroll
    for (int n = 0; n < 2; ++n) {
      bh[n] = *(const bf16x8*)&wHT[n * 16 + lr][kt * 32 + lg * 8];
      bl[n] = *(const bf16x8*)&wLT[n * 16 + lr][kt * 32 + lg * 8];
    }
    if (kt < 7) {
#pragma unroll
      for (int m = 0; m < 2; ++m)
#pragma unroll
        for (int i = 0; i < 8; ++i)
          avN[m][i] = wcb[(size_t)((kt + 1) * 32 + lg * 8 + i) * kC + c0 + m * 16 + lr];
    }
#pragma unroll
    for (int m = 0; m < 2; ++m) {
      bf16x8 ah, al;
#pragma unroll
      for (int i = 0; i < 8; ++i) {
        const ushort h = f2bf(avC[m][i]);
        ah[i] = (short)h;
        al[i] = (short)f2bf(avC[m][i] - bf2f(h));
      }
#pragma unroll
      for (int n = 0; n < 2; ++n) {
        acc[m][n] = MFMA16(ah, bh[n], acc[m][n]);
        acc[m][n] = MFMA16(ah, bl[n], acc[m][n]);
        acc[m][n] = MFMA16(al, bh[n], acc[m][n]);
      }
    }
    if (kt < 7) {
#pragma unroll
      for (int m = 0; m < 2; ++m)
#pragma unroll
        for (int i = 0; i < 8; ++i) avC[m][i] = avN[m][i];
    }
  }

  // ---- softmax over s (rows c = c0+m*16+lg*4+j; cols s=lr, 16+lr) ----
  float* attnb = attn_out + ((size_t)b * kC + cb) * kS;
#pragma unroll
  for (int m = 0; m < 2; ++m) {
#pragma unroll
    for (int j = 0; j < 4; ++j) {
      float v0 = acc[m][0][j], v1 = acc[m][1][j];
      float mx = fmaxf(v0, v1);
      mx = fmaxf(mx, __shfl_xor(mx, 1));
      mx = fmaxf(mx, __shfl_xor(mx, 2));
      mx = fmaxf(mx, __shfl_xor(mx, 4));
      mx = fmaxf(mx, __shfl_xor(mx, 8));
      float e0 = __expf(v0 - mx), e1 = __expf(v1 - mx);
      float sm = e0 + e1;
      sm += __shfl_xor(sm, 1); sm += __shfl_xor(sm, 2);
      sm += __shfl_xor(sm, 4); sm += __shfl_xor(sm, 8);
      const float inv = 1.f / sm;
      e0 *= inv; e1 *= inv;
      const int cL = wave * 32 + m * 16 + lg * 4 + j;
      attnb[(size_t)cL * kS + lr]      = e0;
      attnb[(size_t)cL * kS + 16 + lr] = e1;
      pHl[cL][lr]      = f2bf(e0);
      pHl[cL][16 + lr] = f2bf(e1);
    }
  }
  __syncthreads();   // phase B reads other waves' P rows

  // ======= Phase B: D[p][c] = weT(hi) x P(hi); K=32 =======
  const bf16x8 ahB0 = *(const bf16x8*)&wHp[p0 + lr][lg * 8];
  const bf16x8 ahB1 = *(const bf16x8*)&wHp[p0 + 16 + lr][lg * 8];
  float* outb = out + (size_t)b * kHW * kC + cb;

  bf16x8 pbC = *(const bf16x8*)&pHl[lr][lg * 8];
#pragma unroll 1
  for (int ct = 0; ct < 16; ++ct) {
    bf16x8 pbN;
    if (ct < 15) pbN = *(const bf16x8*)&pHl[(ct + 1) * 16 + lr][lg * 8];
    f32x4 o0 = (f32x4){0.f, 0.f, 0.f, 0.f};
    f32x4 o1 = (f32x4){0.f, 0.f, 0.f, 0.f};
    o0 = MFMA16(ahB0, pbC, o0);
    o1 = MFMA16(ahB1, pbC, o1);
    const int ccol = ct * 16 + lr;
#pragma unroll
    for (int j = 0; j < 4; ++j) {
      outb[(size_t)(p0 + lg * 4 + j) * kC + ccol]      = o0[j];
      outb[(size_t)(p0 + 16 + lg * 4 + j) * kC + ccol] = o1[j];
    }
    pbC = pbN;
  }
}

extern "C" void kernel_launch(void* const* d_in, const int* in_sizes, int n_in,
                              void* d_out, int out_size, void* d_ws, size_t ws_size,
                              hipStream_t stream) {
  const float* wc   = (const float*)d_in[0];
  const float* emb  = (const float*)d_in[1];
  const float* Km   = (const float*)d_in[2];
  const float* bias = (const float*)d_in[3];

  float* out  = (float*)d_out;
  float* attn = out + (size_t)kB * kHW * kC;
  ushort* kmh = (ushort*)d_ws;                 // 128 KB
  ushort* kml = kmh + (size_t)kHW * kE;        // 128 KB

  km_prep_kernel<<<dim3(kHW), 256, 0, stream>>>(Km, kmh, kml);
  fused_attn_kernel<<<dim3(4, kB), 512, 0, stream>>>(wc, emb, kmh, kml, bias,
                                                     out, attn);
}